// Round 4
// baseline (108.500 us; speedup 1.0000x reference)
//
#include <hip/hip_runtime.h>
#include <math.h>

static constexpr int H = 512, W = 512, NPTS = 19, BATCH = 4;
static constexpr int HW = H * W;
static constexpr int NPLANES = BATCH * NPTS;                 // 76
static constexpr long long TOTAL = (long long)NPLANES * HW;  // 19,922,944 per channel group
static constexpr float INV_OFF = 1.0f / 40.0f;

static constexpr int BLOCKSX = 16;                 // 16*76 = 1216 blocks = 4864 waves (all resident)
static constexpr int NVEC = HW / 4;                // 65536 float4 per plane
static constexpr int SITER = NVEC / (BLOCKSX * 256);  // 16 steps/thread, compile-time
static constexpr unsigned int NBLOCKS = BLOCKSX * NPLANES;   // 1216

// ws layout: [0..3] double accumulators (bce, lx, ly, cnt), [4] = u32 ticket.
// Zeroed by hipMemsetAsync each launch (capture-safe), so replays are clean.
//
// Each (b,n) plane: BLOCKSX blocks, each owning a contiguous chunk of
// SITER*256 float4s per stream. Register double-buffer: loads for step s+1
// are issued before computing step s, so 3 dwordx4 stay in flight under the
// transcendental work. Targets computed analytically from the landmark.
// Final reduction fused via device-scope f64 atomics + last-block ticket.
__global__ __launch_bounds__(256) void homl_main(
    const float* __restrict__ fm, const int* __restrict__ lm,
    double* __restrict__ acc, float* __restrict__ out)
{
    const int bn = blockIdx.y;             // 0..75
    const int b  = bn / NPTS;
    const int n  = bn % NPTS;

    int x = lm[bn * 2 + 0];
    int y = lm[bn * 2 + 1];
    x = min(max(x, 1), W - 1);             // clamp_landmarks
    y = min(max(y, 1), H - 1);

    const float* ph_base = fm + ((size_t)b * 3 * NPTS + n) * HW;
    const float* px_base = ph_base + (size_t)NPTS * HW;
    const float* py_base = px_base + (size_t)NPTS * HW;

    const int v0 = blockIdx.x * (SITER * 256) + threadIdx.x;   // vec index, step stride 256

    float bce = 0.0f, lxs = 0.0f, lys = 0.0f, cntf = 0.0f;

    float4 bufA[2], bufB[2], bufC[2];
    {
        const int p = v0 * 4;
        bufA[0] = *reinterpret_cast<const float4*>(ph_base + p);
        bufB[0] = *reinterpret_cast<const float4*>(px_base + p);
        bufC[0] = *reinterpret_cast<const float4*>(py_base + p);
    }

    #pragma unroll
    for (int s = 0; s < SITER; ++s) {
        const int cur = s & 1, nxt = cur ^ 1;      // compile-time under full unroll
        if (s + 1 < SITER) {
            const int p = (v0 + (s + 1) * 256) * 4;
            bufA[nxt] = *reinterpret_cast<const float4*>(ph_base + p);
            bufB[nxt] = *reinterpret_cast<const float4*>(px_base + p);
            bufC[nxt] = *reinterpret_cast<const float4*>(py_base + p);
        }

        const int p   = (v0 + s * 256) * 4;
        const int i   = p >> 9;                    // row (W = 512)
        const int j   = p & (W - 1);               // col of first of 4
        const int dy  = i - y;
        const int dy2 = dy * dy;
        const float tx = (float)(y - i) * INV_OFF; // offmap_x target (same for all 4)

        const float pha[4] = {bufA[cur].x, bufA[cur].y, bufA[cur].z, bufA[cur].w};
        const float pxa[4] = {bufB[cur].x, bufB[cur].y, bufB[cur].z, bufB[cur].w};
        const float pya[4] = {bufC[cur].x, bufC[cur].y, bufC[cur].z, bufC[cur].w};

        #pragma unroll
        for (int k = 0; k < 4; ++k) {
            const int dx = j + k - x;
            const int d2 = dy2 + dx * dx;
            const float ph = pha[k];
            // stable BCE-with-logits via native exp2/log2:
            // max(ph,0) - ph*th + ln2 * log2(1 + 2^(-|ph|*log2e))
            const float a  = fabsf(ph);
            const float sp = 0.69314718056f *
                             log2f(1.0f + exp2f(-1.44269504089f * a));
            bce += fmaxf(ph, 0.0f) + sp;

            const bool in = (d2 <= 1600);          // th == 1, ind == 1
            bce  -= in ? ph : 0.0f;
            cntf += in ? 1.0f : 0.0f;
            const float ty = (float)(x - (j + k)) * INV_OFF;
            lxs += in ? fabsf(pxa[k] - tx) : 0.0f;
            lys += in ? fabsf(pya[k] - ty) : 0.0f;
        }
    }

    // wave (64-lane) reduction
    #pragma unroll
    for (int off = 32; off > 0; off >>= 1) {
        bce  += __shfl_down(bce, off);
        lxs  += __shfl_down(lxs, off);
        lys  += __shfl_down(lys, off);
        cntf += __shfl_down(cntf, off);
    }

    __shared__ float redf[4][4];
    const int wave = threadIdx.x >> 6;
    const int lane = threadIdx.x & 63;
    if (lane == 0) {
        redf[0][wave] = bce; redf[1][wave] = lxs;
        redf[2][wave] = lys; redf[3][wave] = cntf;
    }
    __syncthreads();
    if (threadIdx.x == 0) {
        double db = 0.0, dxs = 0.0, dys = 0.0, dc = 0.0;
        #pragma unroll
        for (int wv = 0; wv < 4; ++wv) {
            db  += (double)redf[0][wv];
            dxs += (double)redf[1][wv];
            dys += (double)redf[2][wv];
            dc  += (double)redf[3][wv];
        }
        atomicAdd(&acc[0], db);
        atomicAdd(&acc[1], dxs);
        atomicAdd(&acc[2], dys);
        atomicAdd(&acc[3], dc);
        __threadfence();                           // release partial sums
        unsigned int* ticket = reinterpret_cast<unsigned int*>(acc + 4);
        const unsigned int old = atomicAdd(ticket, 1u);
        if (old == NBLOCKS - 1) {                  // last block to finish
            __threadfence();                       // acquire
            const double tb  = atomicAdd(&acc[0], 0.0);  // coherent reads
            const double txs = atomicAdd(&acc[1], 0.0);
            const double tys = atomicAdd(&acc[2], 0.0);
            const double tc  = atomicAdd(&acc[3], 0.0);
            const double bce_mean = tb / (double)TOTAL;
            out[0] = (float)(2.0 * bce_mean + txs / tc + tys / tc);
        }
    }
}

extern "C" void kernel_launch(void* const* d_in, const int* in_sizes, int n_in,
                              void* d_out, int out_size, void* d_ws, size_t ws_size,
                              hipStream_t stream) {
    const float* fm  = (const float*)d_in[0];
    const int*   lm  = (const int*)d_in[1];
    float*       out = (float*)d_out;
    double*      ws  = (double*)d_ws;

    // zero the 4 f64 accumulators + ticket counter (capture-safe stream op)
    hipMemsetAsync(d_ws, 0, 64, stream);

    dim3 grid(BLOCKSX, NPLANES);
    homl_main<<<grid, 256, 0, stream>>>(fm, lm, ws, out);
}

// Round 5
// 27.175 us; speedup vs baseline: 3.9926x; 3.9926x over previous
//
#include <hip/hip_runtime.h>
#include <math.h>

static constexpr int H = 512, W = 512, NPTS = 19, BATCH = 4;
static constexpr int HW = H * W;
static constexpr int NPLANES = BATCH * NPTS;                 // 76
static constexpr long long TOTAL = (long long)NPLANES * HW;  // 19,922,944 per channel group
static constexpr float INV_OFF = 1.0f / 40.0f;

static constexpr int BX_BULK = 16;                    // bulk blocks per plane (BCE over ph)
static constexpr int BX_DISK = 8;                     // disk blocks per plane (L1 over 81x81 box)
static constexpr int BX      = BX_BULK + BX_DISK;     // 24
static constexpr int SITER   = (HW / 4) / (BX_BULK * 256);   // 16 float4 steps/thread
static constexpr int NBULK   = BX_BULK * NPLANES;     // 1216 bce partials (double each)
static constexpr int NDISK   = BX_DISK * NPLANES;     // 608 disk partials (double4 each)
// ws layout: [0 .. NBULK) doubles = bce partials;
//            then NDISK double4 = (lx, ly, cnt, 0). All slots written every launch.

__global__ __launch_bounds__(256) void homl_main(
    const float* __restrict__ fm, const int* __restrict__ lm,
    double* __restrict__ ws_)
{
    const int bn = blockIdx.y;             // 0..75
    const int b  = bn / NPTS;
    const int n  = bn % NPTS;

    int x = lm[bn * 2 + 0];
    int y = lm[bn * 2 + 1];
    x = min(max(x, 1), W - 1);             // clamp_landmarks
    y = min(max(y, 1), H - 1);

    __shared__ float redf[4][4];
    const int wave = threadIdx.x >> 6;
    const int lane = threadIdx.x & 63;

    if (blockIdx.x < BX_BULK) {
        // ---------------- bulk BCE over the heat-logit plane ----------------
        const float* ph_base = fm + ((size_t)b * 3 * NPTS + n) * HW;
        const int v0 = blockIdx.x * (SITER * 256) + threadIdx.x;  // step stride 256

        float bce = 0.0f;
        float4 buf[4];                         // 4-deep register pipeline
        #pragma unroll
        for (int s0 = 0; s0 < 3; ++s0)
            buf[s0] = *reinterpret_cast<const float4*>(ph_base + (v0 + s0 * 256) * 4);

        #pragma unroll
        for (int s = 0; s < SITER; ++s) {
            if (s + 3 < SITER)                 // prefetch 3 steps ahead
                buf[(s + 3) & 3] = *reinterpret_cast<const float4*>(
                    ph_base + (v0 + (s + 3) * 256) * 4);

            const int p   = (v0 + s * 256) * 4;
            const int i   = p >> 9;            // row (W = 512)
            const int j   = p & (W - 1);       // col of first of 4
            const int dy  = i - y;
            const int dy2 = dy * dy;

            const float pha[4] = {buf[s & 3].x, buf[s & 3].y, buf[s & 3].z, buf[s & 3].w};
            #pragma unroll
            for (int k = 0; k < 4; ++k) {
                const int dx = j + k - x;
                const int d2 = dy2 + dx * dx;
                const float ph = pha[k];
                // stable BCE-with-logits via native exp2/log2:
                // max(ph,0) - ph*th + ln2 * log2(1 + 2^(-|ph|*log2e))
                const float a  = fabsf(ph);
                const float sp = 0.69314718056f *
                                 log2f(1.0f + exp2f(-1.44269504089f * a));
                bce += fmaxf(ph, 0.0f) + sp;
                bce -= (d2 <= 1600) ? ph : 0.0f;   // th == 1 inside disk
            }
        }

        #pragma unroll
        for (int off = 32; off > 0; off >>= 1) bce += __shfl_down(bce, off);
        if (lane == 0) redf[0][wave] = bce;
        __syncthreads();
        if (threadIdx.x == 0) {
            double db = 0.0;
            #pragma unroll
            for (int wv = 0; wv < 4; ++wv) db += (double)redf[0][wv];
            ws_[bn * BX_BULK + blockIdx.x] = db;
        }
    } else {
        // ---------------- disk L1 over the 81x81 landmark box ----------------
        const int dblk = blockIdx.x - BX_BULK;          // 0..7
        const float* px_base = fm + ((size_t)b * 3 * NPTS + NPTS + n) * HW;
        const float* py_base = fm + ((size_t)b * 3 * NPTS + 2 * NPTS + n) * HW;

        const int rbeg = dblk * 11;                     // box rows for this block
        const int rcnt = min(11, 81 - rbeg);            // 11 (or 4 for last block)

        float lxs = 0.0f, lys = 0.0f, cntf = 0.0f;
        for (int idx = threadIdx.x; idx < rcnt * 81; idx += 256) {
            const int rr = idx / 81;                    // magic-mul div
            const int cc = idx - rr * 81;
            const int dy = rbeg + rr - 40;              // r - y
            const int dx = cc - 40;                     // c - x
            const int r  = y + dy;
            const int c  = x + dx;
            if (r >= 0 && r < H && c >= 0 && c < W && dy * dy + dx * dx <= 1600) {
                const float tx = (float)(-dy) * INV_OFF;   // (y - r)/40
                const float ty = (float)(-dx) * INV_OFF;   // (x - c)/40
                const size_t off = (size_t)r * W + c;
                lxs  += fabsf(px_base[off] - tx);
                lys  += fabsf(py_base[off] - ty);
                cntf += 1.0f;
            }
        }

        #pragma unroll
        for (int off = 32; off > 0; off >>= 1) {
            lxs  += __shfl_down(lxs, off);
            lys  += __shfl_down(lys, off);
            cntf += __shfl_down(cntf, off);
        }
        if (lane == 0) { redf[1][wave] = lxs; redf[2][wave] = lys; redf[3][wave] = cntf; }
        __syncthreads();
        if (threadIdx.x == 0) {
            double dxs = 0.0, dys = 0.0, dc = 0.0;
            #pragma unroll
            for (int wv = 0; wv < 4; ++wv) {
                dxs += (double)redf[1][wv];
                dys += (double)redf[2][wv];
                dc  += (double)redf[3][wv];
            }
            double4 o; o.x = dxs; o.y = dys; o.z = dc; o.w = 0.0;
            *reinterpret_cast<double4*>(ws_ + NBULK + (size_t)(bn * BX_DISK + dblk) * 4) = o;
        }
    }
}

__global__ __launch_bounds__(256) void homl_final(
    const double* __restrict__ ws_, float* __restrict__ out)
{
    double bs = 0.0, xs = 0.0, ys = 0.0, c = 0.0;
    for (int i = threadIdx.x; i < NBULK; i += 256) bs += ws_[i];
    const double* dp = ws_ + NBULK;
    for (int i = threadIdx.x; i < NDISK; i += 256) {
        xs += dp[(size_t)i * 4 + 0];
        ys += dp[(size_t)i * 4 + 1];
        c  += dp[(size_t)i * 4 + 2];
    }
    #pragma unroll
    for (int off = 32; off > 0; off >>= 1) {
        bs += __shfl_down(bs, off);
        xs += __shfl_down(xs, off);
        ys += __shfl_down(ys, off);
        c  += __shfl_down(c, off);
    }
    __shared__ double sd[4][4];
    const int wave = threadIdx.x >> 6;
    const int lane = threadIdx.x & 63;
    if (lane == 0) { sd[0][wave] = bs; sd[1][wave] = xs; sd[2][wave] = ys; sd[3][wave] = c; }
    __syncthreads();
    if (threadIdx.x == 0) {
        double tb = 0.0, txs = 0.0, tys = 0.0, tc = 0.0;
        #pragma unroll
        for (int wv = 0; wv < 4; ++wv) {
            tb += sd[0][wv]; txs += sd[1][wv]; tys += sd[2][wv]; tc += sd[3][wv];
        }
        const double bce_mean = tb / (double)TOTAL;
        out[0] = (float)(2.0 * bce_mean + txs / tc + tys / tc);
    }
}

extern "C" void kernel_launch(void* const* d_in, const int* in_sizes, int n_in,
                              void* d_out, int out_size, void* d_ws, size_t ws_size,
                              hipStream_t stream) {
    const float* fm  = (const float*)d_in[0];
    const int*   lm  = (const int*)d_in[1];
    float*       out = (float*)d_out;
    double*      ws  = (double*)d_ws;   // needs (1216 + 608*4)*8 = 29,184 B

    dim3 grid(BX, NPLANES);             // 24 x 76 = 1824 blocks
    homl_main<<<grid, 256, 0, stream>>>(fm, lm, ws);
    homl_final<<<1, 256, 0, stream>>>(ws, out);
}

// Round 6
// 26.935 us; speedup vs baseline: 4.0283x; 1.0089x over previous
//
#include <hip/hip_runtime.h>
#include <math.h>

static constexpr int H = 512, W = 512, NPTS = 19, BATCH = 4;
static constexpr int HW = H * W;
static constexpr int NPLANES = BATCH * NPTS;                 // 76
static constexpr long long TOTAL = (long long)NPLANES * HW;  // 19,922,944 per channel group
static constexpr float INV_OFF = 1.0f / 40.0f;

static constexpr int BLOCKSX = 16;                    // uniform: 16*76 = 1216 blocks
static constexpr int SITER   = (HW / 4) / (BLOCKSX * 256);   // 16 float4 steps/thread
static constexpr int NSLOTS  = BLOCKSX * NPLANES;     // 1216 double4 partials

// One block kind. Each block: (a) issues its share of the 81x81 landmark-box
// loads (px/py, scattered) into registers, (b) streams its contiguous chunk
// of the heat-logit plane for BCE with a 4-deep register pipeline (the
// scattered loads complete underneath), (c) folds the disk L1 terms in, and
// (d) writes one double4 partial (bce, lx, ly, cnt). No atomics, all slots
// written every launch -> deterministic, no memset needed.
__global__ __launch_bounds__(256) void homl_main(
    const float* __restrict__ fm, const int* __restrict__ lm,
    double* __restrict__ ws_)
{
    const int bn = blockIdx.y;             // 0..75
    const int bx = blockIdx.x;             // 0..15
    const int b  = bn / NPTS;
    const int n  = bn % NPTS;

    int x = lm[bn * 2 + 0];
    int y = lm[bn * 2 + 1];
    x = min(max(x, 1), W - 1);             // clamp_landmarks
    y = min(max(y, 1), H - 1);

    const float* ph_base = fm + ((size_t)b * 3 * NPTS + n) * HW;
    const float* px_base = ph_base + (size_t)NPTS * HW;
    const float* py_base = px_base + (size_t)NPTS * HW;

    // ---- disk prelude: issue scattered box loads early (complete under bulk) ----
    // Box rows handled by this block: brow = bx + 16*rr, rr = 0..nrows-1.
    const int nrows = (bx == 0) ? 6 : 5;   // 81 rows split round-robin over 16 blocks
    float pxv[2], pyv[2], txv[2], tyv[2];
    bool  val[2];
    #pragma unroll
    for (int t = 0; t < 2; ++t) {
        const int idx = threadIdx.x + t * 256;     // 0..511, need < nrows*81
        const int rr  = idx / 81;
        const int cc  = idx - rr * 81;
        const int brow = bx + 16 * rr;             // 0..80
        const int dy  = brow - 40;                 // r - y
        const int dx  = cc - 40;                   // c - x
        const int r   = y + dy;
        const int c   = x + dx;
        const bool v  = (rr < nrows) && (r >= 0) && (r < H) &&
                        (c >= 0) && (c < W) && (dy * dy + dx * dx <= 1600);
        const size_t off = v ? ((size_t)r * W + c) : 0;   // branchless safe addr
        pxv[t] = px_base[off];
        pyv[t] = py_base[off];
        txv[t] = (float)(-dy) * INV_OFF;           // (y - r)/40
        tyv[t] = (float)(-dx) * INV_OFF;           // (x - c)/40
        val[t] = v;
    }

    // ---- bulk BCE over the heat-logit plane (4-deep register pipeline) ----
    const int v0 = bx * (SITER * 256) + threadIdx.x;   // step stride 256

    float bce = 0.0f;
    float4 buf[4];
    #pragma unroll
    for (int s0 = 0; s0 < 3; ++s0)
        buf[s0] = *reinterpret_cast<const float4*>(ph_base + (v0 + s0 * 256) * 4);

    #pragma unroll
    for (int s = 0; s < SITER; ++s) {
        if (s + 3 < SITER)                 // prefetch 3 steps ahead
            buf[(s + 3) & 3] = *reinterpret_cast<const float4*>(
                ph_base + (v0 + (s + 3) * 256) * 4);

        const int p   = (v0 + s * 256) * 4;
        const int i   = p >> 9;            // row (W = 512)
        const int j   = p & (W - 1);       // col of first of 4
        const int dyb = i - y;
        const int dy2 = dyb * dyb;

        const float pha[4] = {buf[s & 3].x, buf[s & 3].y, buf[s & 3].z, buf[s & 3].w};
        #pragma unroll
        for (int k = 0; k < 4; ++k) {
            const int dx = j + k - x;
            const int d2 = dy2 + dx * dx;
            const float ph = pha[k];
            // stable BCE-with-logits via native exp2/log2:
            // max(ph,0) - ph*th + ln2 * log2(1 + 2^(-|ph|*log2e))
            const float a  = fabsf(ph);
            const float sp = 0.69314718056f *
                             log2f(1.0f + exp2f(-1.44269504089f * a));
            bce += fmaxf(ph, 0.0f) + sp;
            bce -= (d2 <= 1600) ? ph : 0.0f;   // th == 1 inside disk
        }
    }

    // ---- disk combine (loads long since landed) ----
    float lxs = 0.0f, lys = 0.0f, cntf = 0.0f;
    #pragma unroll
    for (int t = 0; t < 2; ++t) {
        if (val[t]) {
            lxs  += fabsf(pxv[t] - txv[t]);
            lys  += fabsf(pyv[t] - tyv[t]);
            cntf += 1.0f;
        }
    }

    // ---- joint reduction: wave shuffle, then cross-wave via LDS ----
    #pragma unroll
    for (int off = 32; off > 0; off >>= 1) {
        bce  += __shfl_down(bce, off);
        lxs  += __shfl_down(lxs, off);
        lys  += __shfl_down(lys, off);
        cntf += __shfl_down(cntf, off);
    }

    __shared__ float redf[4][4];
    const int wave = threadIdx.x >> 6;
    const int lane = threadIdx.x & 63;
    if (lane == 0) {
        redf[0][wave] = bce; redf[1][wave] = lxs;
        redf[2][wave] = lys; redf[3][wave] = cntf;
    }
    __syncthreads();
    if (threadIdx.x == 0) {
        double db = 0.0, dxs = 0.0, dys = 0.0, dc = 0.0;
        #pragma unroll
        for (int wv = 0; wv < 4; ++wv) {
            db  += (double)redf[0][wv];
            dxs += (double)redf[1][wv];
            dys += (double)redf[2][wv];
            dc  += (double)redf[3][wv];
        }
        double4 o; o.x = db; o.y = dxs; o.z = dys; o.w = dc;
        *reinterpret_cast<double4*>(ws_ + (size_t)(bn * BLOCKSX + bx) * 4) = o;
    }
}

__global__ __launch_bounds__(256) void homl_final(
    const double* __restrict__ ws_, float* __restrict__ out)
{
    double bs = 0.0, xs = 0.0, ys = 0.0, c = 0.0;
    for (int i = threadIdx.x; i < NSLOTS; i += 256) {
        const double4 p = *reinterpret_cast<const double4*>(ws_ + (size_t)i * 4);
        bs += p.x; xs += p.y; ys += p.z; c += p.w;
    }
    #pragma unroll
    for (int off = 32; off > 0; off >>= 1) {
        bs += __shfl_down(bs, off);
        xs += __shfl_down(xs, off);
        ys += __shfl_down(ys, off);
        c  += __shfl_down(c, off);
    }
    __shared__ double sd[4][4];
    const int wave = threadIdx.x >> 6;
    const int lane = threadIdx.x & 63;
    if (lane == 0) { sd[0][wave] = bs; sd[1][wave] = xs; sd[2][wave] = ys; sd[3][wave] = c; }
    __syncthreads();
    if (threadIdx.x == 0) {
        double tb = 0.0, txs = 0.0, tys = 0.0, tc = 0.0;
        #pragma unroll
        for (int wv = 0; wv < 4; ++wv) {
            tb += sd[0][wv]; txs += sd[1][wv]; tys += sd[2][wv]; tc += sd[3][wv];
        }
        const double bce_mean = tb / (double)TOTAL;
        out[0] = (float)(2.0 * bce_mean + txs / tc + tys / tc);
    }
}

extern "C" void kernel_launch(void* const* d_in, const int* in_sizes, int n_in,
                              void* d_out, int out_size, void* d_ws, size_t ws_size,
                              hipStream_t stream) {
    const float* fm  = (const float*)d_in[0];
    const int*   lm  = (const int*)d_in[1];
    float*       out = (float*)d_out;
    double*      ws  = (double*)d_ws;   // needs 1216 * 32 = 38,912 B

    dim3 grid(BLOCKSX, NPLANES);        // 16 x 76 = 1216 uniform blocks
    homl_main<<<grid, 256, 0, stream>>>(fm, lm, ws);
    homl_final<<<1, 256, 0, stream>>>(ws, out);
}

// Round 7
// 26.250 us; speedup vs baseline: 4.1333x; 1.0261x over previous
//
#include <hip/hip_runtime.h>
#include <math.h>

static constexpr int H = 512, W = 512, NPTS = 19, BATCH = 4;
static constexpr int HW = H * W;
static constexpr int NPLANES = BATCH * NPTS;                 // 76
static constexpr long long TOTAL = (long long)NPLANES * HW;  // 19,922,944 per channel group
static constexpr float INV_OFF = 1.0f / 40.0f;

static constexpr int BLOCKSX = 16;                    // uniform: 16*76 = 1216 blocks
static constexpr int SITER   = (HW / 8) / (BLOCKSX * 256);   // 8 steps, 2 float4/thread/step
static constexpr int DEPTH   = 4;                     // pipeline slots (pairs) -> ~128B/thread in flight
static constexpr int NSLOTS  = BLOCKSX * NPLANES;     // 1216 double4 partials

// Each block: (a) issues its share of the 81x81 landmark-box loads (px/py,
// scattered) into registers, (b) streams its contiguous 64KB chunk of the
// heat-logit plane for BCE with a 4-slot x 2-float4 register pipeline
// (~8 dwordx4 in flight per thread), (c) folds the disk L1 terms in,
// (d) writes one double4 partial (bce, lx, ly, cnt). No atomics, all slots
// written every launch -> deterministic, no memset needed.
__global__ __launch_bounds__(256) void homl_main(
    const float* __restrict__ fm, const int* __restrict__ lm,
    double* __restrict__ ws_)
{
    const int bn = blockIdx.y;             // 0..75
    const int bx = blockIdx.x;             // 0..15
    const int b  = bn / NPTS;
    const int n  = bn % NPTS;

    int x = lm[bn * 2 + 0];
    int y = lm[bn * 2 + 1];
    x = min(max(x, 1), W - 1);             // clamp_landmarks
    y = min(max(y, 1), H - 1);

    const float* ph_base = fm + ((size_t)b * 3 * NPTS + n) * HW;
    const float* px_base = ph_base + (size_t)NPTS * HW;
    const float* py_base = px_base + (size_t)NPTS * HW;

    // ---- disk prelude: issue scattered box loads early (complete under bulk) ----
    // Box rows handled by this block: brow = bx + 16*rr, rr = 0..nrows-1.
    const int nrows = (bx == 0) ? 6 : 5;   // 81 rows split round-robin over 16 blocks
    float pxv[2], pyv[2], txv[2], tyv[2];
    bool  val[2];
    #pragma unroll
    for (int t = 0; t < 2; ++t) {
        const int idx = threadIdx.x + t * 256;     // 0..511, need < nrows*81
        const int rr  = idx / 81;
        const int cc  = idx - rr * 81;
        const int brow = bx + 16 * rr;             // 0..80
        const int dy  = brow - 40;                 // r - y
        const int dx  = cc - 40;                   // c - x
        const int r   = y + dy;
        const int c   = x + dx;
        const bool v  = (rr < nrows) && (r >= 0) && (r < H) &&
                        (c >= 0) && (c < W) && (dy * dy + dx * dx <= 1600);
        const size_t off = v ? ((size_t)r * W + c) : 0;   // branchless safe addr
        pxv[t] = px_base[off];
        pyv[t] = py_base[off];
        txv[t] = (float)(-dy) * INV_OFF;           // (y - r)/40
        tyv[t] = (float)(-dx) * INV_OFF;           // (x - c)/40
        val[t] = v;
    }

    // ---- bulk BCE: 8 steps x (2 float4)/thread, 4-slot register pipeline ----
    // Block chunk = 64KB. Step s chunk = 8KB = 2048 floats: thread t owns
    // float4 #t (low) and #(t+256) (high) of the step chunk.
    const int tbase = bx * (SITER * 2048) + (int)threadIdx.x * 4;  // float index

    float bce = 0.0f;
    float4 bl[DEPTH], bh[DEPTH];
    #pragma unroll
    for (int s0 = 0; s0 < DEPTH; ++s0) {
        bl[s0] = *reinterpret_cast<const float4*>(ph_base + tbase + s0 * 2048);
        bh[s0] = *reinterpret_cast<const float4*>(ph_base + tbase + s0 * 2048 + 1024);
    }

    #pragma unroll
    for (int s = 0; s < SITER; ++s) {
        const float4 a0 = bl[s & (DEPTH - 1)];
        const float4 a1 = bh[s & (DEPTH - 1)];
        if (s + DEPTH < SITER) {               // refill the just-freed slot
            bl[s & (DEPTH - 1)] = *reinterpret_cast<const float4*>(
                ph_base + tbase + (s + DEPTH) * 2048);
            bh[s & (DEPTH - 1)] = *reinterpret_cast<const float4*>(
                ph_base + tbase + (s + DEPTH) * 2048 + 1024);
        }

        #pragma unroll
        for (int half = 0; half < 2; ++half) {
            const int p   = tbase + s * 2048 + half * 1024;
            const int i   = p >> 9;            // row (W = 512)
            const int j   = p & (W - 1);       // col of first of 4
            const int dyb = i - y;
            const int dy2 = dyb * dyb;
            const float4 q = half ? a1 : a0;
            const float pha[4] = {q.x, q.y, q.z, q.w};
            #pragma unroll
            for (int k = 0; k < 4; ++k) {
                const int dx = j + k - x;
                const int d2 = dy2 + dx * dx;
                const float ph = pha[k];
                // stable BCE-with-logits via native exp2/log2:
                // max(ph,0) - ph*th + ln2 * log2(1 + 2^(-|ph|*log2e))
                const float a  = fabsf(ph);
                const float sp = 0.69314718056f *
                                 log2f(1.0f + exp2f(-1.44269504089f * a));
                bce += fmaxf(ph, 0.0f) + sp;
                bce -= (d2 <= 1600) ? ph : 0.0f;   // th == 1 inside disk
            }
        }
    }

    // ---- disk combine (loads long since landed) ----
    float lxs = 0.0f, lys = 0.0f, cntf = 0.0f;
    #pragma unroll
    for (int t = 0; t < 2; ++t) {
        if (val[t]) {
            lxs  += fabsf(pxv[t] - txv[t]);
            lys  += fabsf(pyv[t] - tyv[t]);
            cntf += 1.0f;
        }
    }

    // ---- joint reduction: wave shuffle, then cross-wave via LDS ----
    #pragma unroll
    for (int off = 32; off > 0; off >>= 1) {
        bce  += __shfl_down(bce, off);
        lxs  += __shfl_down(lxs, off);
        lys  += __shfl_down(lys, off);
        cntf += __shfl_down(cntf, off);
    }

    __shared__ float redf[4][4];
    const int wave = threadIdx.x >> 6;
    const int lane = threadIdx.x & 63;
    if (lane == 0) {
        redf[0][wave] = bce; redf[1][wave] = lxs;
        redf[2][wave] = lys; redf[3][wave] = cntf;
    }
    __syncthreads();
    if (threadIdx.x == 0) {
        double db = 0.0, dxs = 0.0, dys = 0.0, dc = 0.0;
        #pragma unroll
        for (int wv = 0; wv < 4; ++wv) {
            db  += (double)redf[0][wv];
            dxs += (double)redf[1][wv];
            dys += (double)redf[2][wv];
            dc  += (double)redf[3][wv];
        }
        double4 o; o.x = db; o.y = dxs; o.z = dys; o.w = dc;
        *reinterpret_cast<double4*>(ws_ + (size_t)(bn * BLOCKSX + bx) * 4) = o;
    }
}

__global__ __launch_bounds__(256) void homl_final(
    const double* __restrict__ ws_, float* __restrict__ out)
{
    double bs = 0.0, xs = 0.0, ys = 0.0, c = 0.0;
    for (int i = threadIdx.x; i < NSLOTS; i += 256) {
        const double4 p = *reinterpret_cast<const double4*>(ws_ + (size_t)i * 4);
        bs += p.x; xs += p.y; ys += p.z; c += p.w;
    }
    #pragma unroll
    for (int off = 32; off > 0; off >>= 1) {
        bs += __shfl_down(bs, off);
        xs += __shfl_down(xs, off);
        ys += __shfl_down(ys, off);
        c  += __shfl_down(c, off);
    }
    __shared__ double sd[4][4];
    const int wave = threadIdx.x >> 6;
    const int lane = threadIdx.x & 63;
    if (lane == 0) { sd[0][wave] = bs; sd[1][wave] = xs; sd[2][wave] = ys; sd[3][wave] = c; }
    __syncthreads();
    if (threadIdx.x == 0) {
        double tb = 0.0, txs = 0.0, tys = 0.0, tc = 0.0;
        #pragma unroll
        for (int wv = 0; wv < 4; ++wv) {
            tb += sd[0][wv]; txs += sd[1][wv]; tys += sd[2][wv]; tc += sd[3][wv];
        }
        const double bce_mean = tb / (double)TOTAL;
        out[0] = (float)(2.0 * bce_mean + txs / tc + tys / tc);
    }
}

extern "C" void kernel_launch(void* const* d_in, const int* in_sizes, int n_in,
                              void* d_out, int out_size, void* d_ws, size_t ws_size,
                              hipStream_t stream) {
    const float* fm  = (const float*)d_in[0];
    const int*   lm  = (const int*)d_in[1];
    float*       out = (float*)d_out;
    double*      ws  = (double*)d_ws;   // needs 1216 * 32 = 38,912 B

    dim3 grid(BLOCKSX, NPLANES);        // 16 x 76 = 1216 uniform blocks
    homl_main<<<grid, 256, 0, stream>>>(fm, lm, ws);
    homl_final<<<1, 256, 0, stream>>>(ws, out);
}

// Round 8
// 26.156 us; speedup vs baseline: 4.1482x; 1.0036x over previous
//
#include <hip/hip_runtime.h>
#include <math.h>

static constexpr int H = 512, W = 512, NPTS = 19, BATCH = 4;
static constexpr int HW = H * W;
static constexpr int NPLANES = BATCH * NPTS;                 // 76
static constexpr long long TOTAL = (long long)NPLANES * HW;  // 19,922,944 per channel group
static constexpr float INV_OFF = 1.0f / 40.0f;

static constexpr int BLOCKSX = 32;                    // 32*76 = 2432 blocks (~9.5/CU, 32 waves/CU)
static constexpr int SITER   = (HW / 4) / (BLOCKSX * 256);   // 8 float4 steps/thread
static constexpr int DEPTH   = 4;                     // ring slots -> ~64B/thread in flight
static constexpr int NSLOTS  = BLOCKSX * NPLANES;     // 2432 double4 partials

// Each block: (a) issues its share of the 81x81 landmark-box loads (px/py,
// scattered, <=3 rows -> <=243 px, one slot/thread) into registers, (b)
// streams its contiguous 32KB chunk of the heat-logit plane for BCE with a
// 4-slot register ring, (c) folds the disk L1 terms in, (d) writes one
// double4 partial (bce, lx, ly, cnt). No atomics, all slots written every
// launch -> deterministic, no memset needed.
__global__ __launch_bounds__(256) void homl_main(
    const float* __restrict__ fm, const int* __restrict__ lm,
    double* __restrict__ ws_)
{
    const int bn = blockIdx.y;             // 0..75
    const int bx = blockIdx.x;             // 0..31
    const int b  = bn / NPTS;
    const int n  = bn % NPTS;

    int x = lm[bn * 2 + 0];
    int y = lm[bn * 2 + 1];
    x = min(max(x, 1), W - 1);             // clamp_landmarks
    y = min(max(y, 1), H - 1);

    const float* ph_base = fm + ((size_t)b * 3 * NPTS + n) * HW;
    const float* px_base = ph_base + (size_t)NPTS * HW;
    const float* py_base = px_base + (size_t)NPTS * HW;

    // ---- disk prelude: issue scattered box loads early (complete under bulk) ----
    // Box rows for this block: brow = bx + 32*rr, rr = 0..nrows-1 (81 rows total).
    const int nrows = (bx < 17) ? 3 : 2;
    float pxv, pyv, txv, tyv;
    bool  val;
    {
        const int idx = threadIdx.x;               // need < nrows*81 (<= 243)
        const int rr  = idx / 81;
        const int cc  = idx - rr * 81;
        const int brow = bx + 32 * rr;             // 0..80
        const int dy  = brow - 40;                 // r - y
        const int dx  = cc - 40;                   // c - x
        const int r   = y + dy;
        const int c   = x + dx;
        val = (rr < nrows) && (r >= 0) && (r < H) &&
              (c >= 0) && (c < W) && (dy * dy + dx * dx <= 1600);
        const size_t off = val ? ((size_t)r * W + c) : 0;   // branchless safe addr
        pxv = px_base[off];
        pyv = py_base[off];
        txv = (float)(-dy) * INV_OFF;              // (y - r)/40
        tyv = (float)(-dx) * INV_OFF;              // (x - c)/40
    }

    // ---- bulk BCE: 8 steps x 1 float4/thread, 4-slot register ring ----
    // Block chunk = 8192 floats (32KB); step chunk = 1024 floats.
    const int tbase = bx * (SITER * 1024) + (int)threadIdx.x * 4;  // float index

    float bce = 0.0f;
    float4 buf[DEPTH];
    #pragma unroll
    for (int s0 = 0; s0 < DEPTH - 1; ++s0)
        buf[s0] = *reinterpret_cast<const float4*>(ph_base + tbase + s0 * 1024);

    #pragma unroll
    for (int s = 0; s < SITER; ++s) {
        if (s + DEPTH - 1 < SITER)             // prefetch 3 steps ahead
            buf[(s + DEPTH - 1) & (DEPTH - 1)] = *reinterpret_cast<const float4*>(
                ph_base + tbase + (s + DEPTH - 1) * 1024);

        const int p   = tbase + s * 1024;
        const int i   = p >> 9;                // row (W = 512)
        const int j   = p & (W - 1);           // col of first of 4
        const int dyb = i - y;
        const int dy2 = dyb * dyb;

        const float4 q = buf[s & (DEPTH - 1)];
        const float pha[4] = {q.x, q.y, q.z, q.w};
        #pragma unroll
        for (int k = 0; k < 4; ++k) {
            const int dx = j + k - x;
            const int d2 = dy2 + dx * dx;
            const float ph = pha[k];
            // stable BCE-with-logits via native exp2/log2:
            // max(ph,0) - ph*th + ln2 * log2(1 + 2^(-|ph|*log2e))
            const float a  = fabsf(ph);
            const float sp = 0.69314718056f *
                             log2f(1.0f + exp2f(-1.44269504089f * a));
            bce += fmaxf(ph, 0.0f) + sp;
            bce -= (d2 <= 1600) ? ph : 0.0f;   // th == 1 inside disk
        }
    }

    // ---- disk combine (loads long since landed) ----
    float lxs = 0.0f, lys = 0.0f, cntf = 0.0f;
    if (val) {
        lxs  = fabsf(pxv - txv);
        lys  = fabsf(pyv - tyv);
        cntf = 1.0f;
    }

    // ---- joint reduction: wave shuffle, then cross-wave via LDS ----
    #pragma unroll
    for (int off = 32; off > 0; off >>= 1) {
        bce  += __shfl_down(bce, off);
        lxs  += __shfl_down(lxs, off);
        lys  += __shfl_down(lys, off);
        cntf += __shfl_down(cntf, off);
    }

    __shared__ float redf[4][4];
    const int wave = threadIdx.x >> 6;
    const int lane = threadIdx.x & 63;
    if (lane == 0) {
        redf[0][wave] = bce; redf[1][wave] = lxs;
        redf[2][wave] = lys; redf[3][wave] = cntf;
    }
    __syncthreads();
    if (threadIdx.x == 0) {
        double db = 0.0, dxs = 0.0, dys = 0.0, dc = 0.0;
        #pragma unroll
        for (int wv = 0; wv < 4; ++wv) {
            db  += (double)redf[0][wv];
            dxs += (double)redf[1][wv];
            dys += (double)redf[2][wv];
            dc  += (double)redf[3][wv];
        }
        double4 o; o.x = db; o.y = dxs; o.z = dys; o.w = dc;
        *reinterpret_cast<double4*>(ws_ + (size_t)(bn * BLOCKSX + bx) * 4) = o;
    }
}

__global__ __launch_bounds__(256) void homl_final(
    const double* __restrict__ ws_, float* __restrict__ out)
{
    double bs = 0.0, xs = 0.0, ys = 0.0, c = 0.0;
    for (int i = threadIdx.x; i < NSLOTS; i += 256) {
        const double4 p = *reinterpret_cast<const double4*>(ws_ + (size_t)i * 4);
        bs += p.x; xs += p.y; ys += p.z; c += p.w;
    }
    #pragma unroll
    for (int off = 32; off > 0; off >>= 1) {
        bs += __shfl_down(bs, off);
        xs += __shfl_down(xs, off);
        ys += __shfl_down(ys, off);
        c  += __shfl_down(c, off);
    }
    __shared__ double sd[4][4];
    const int wave = threadIdx.x >> 6;
    const int lane = threadIdx.x & 63;
    if (lane == 0) { sd[0][wave] = bs; sd[1][wave] = xs; sd[2][wave] = ys; sd[3][wave] = c; }
    __syncthreads();
    if (threadIdx.x == 0) {
        double tb = 0.0, txs = 0.0, tys = 0.0, tc = 0.0;
        #pragma unroll
        for (int wv = 0; wv < 4; ++wv) {
            tb += sd[0][wv]; txs += sd[1][wv]; tys += sd[2][wv]; tc += sd[3][wv];
        }
        const double bce_mean = tb / (double)TOTAL;
        out[0] = (float)(2.0 * bce_mean + txs / tc + tys / tc);
    }
}

extern "C" void kernel_launch(void* const* d_in, const int* in_sizes, int n_in,
                              void* d_out, int out_size, void* d_ws, size_t ws_size,
                              hipStream_t stream) {
    const float* fm  = (const float*)d_in[0];
    const int*   lm  = (const int*)d_in[1];
    float*       out = (float*)d_out;
    double*      ws  = (double*)d_ws;   // needs 2432 * 32 = 77,824 B

    dim3 grid(BLOCKSX, NPLANES);        // 32 x 76 = 2432 uniform blocks
    homl_main<<<grid, 256, 0, stream>>>(fm, lm, ws);
    homl_final<<<1, 256, 0, stream>>>(ws, out);
}